// Round 8
// baseline (438.012 us; speedup 1.0000x reference)
//
#include <hip/hip_runtime.h>

#define N_IN    128
#define DD      256
#define KSEL    4096
#define NBATCH  8
#define NGROUP  16
#define CHUNKS  16          // scan chunks per group
#define SUBCAP  4096        // candidate sub-range per (group,chunk)
#define CAND_CAP (CHUNKS*SUBCAP)
#define HSLOTS  4           // global hist replica slots per group
#define K1_CPB  250         // kernel-1 blocks per batch
#define K1_ROWS 400         // rows per kernel-1 block
#define USLICE  16          // update-kernel slices per group
#define PSLOT   17          // part slots per group: 16 chunks + 1 tail

// monotone map: float ordering -> unsigned ordering
__device__ __forceinline__ unsigned keyOf(float s){
    unsigned b = __float_as_uint(s);
    return (b & 0x80000000u) ? ~b : (b | 0x80000000u);
}

// ---------------------------------------------------------------------------
// Kernel 0: zero counters + global hist (replaces slow rocclr fill).
// ---------------------------------------------------------------------------
__global__ __launch_bounds__(256) void zero_kernel(uint4* __restrict__ p, int n16)
{
    const int i = blockIdx.x * 256 + threadIdx.x;
    if (i < n16) p[i] = uint4{0u, 0u, 0u, 0u};
}

// ---------------------------------------------------------------------------
// Kernel 1: scores + fused 11-bit histogram + x->out copy. (proven)
// ---------------------------------------------------------------------------
__global__ __launch_bounds__(256) void scores_hist_copy_kernel(
        const float* __restrict__ x, const float* __restrict__ W_fr,
        const float* __restrict__ b_fr, unsigned* __restrict__ keys,
        unsigned* __restrict__ gHist, float* __restrict__ out, int N, int R)
{
    const int b   = blockIdx.x / K1_CPB;
    const int c   = blockIdx.x % K1_CPB;
    const int rbase = b * R + c * K1_ROWS;
    const int tid = threadIdx.x;
    const int wave = tid >> 6, lane = tid & 63;

    __shared__ unsigned h0[2048], h1[2048];
    for (int i = tid; i < 2048; i += 256){ h0[i] = 0u; h1[i] = 0u; }
    __syncthreads();

    const int f = 4 * (lane & 31);
    const float w00 = W_fr[(f+0)*2+0], w01 = W_fr[(f+0)*2+1];
    const float w10 = W_fr[(f+1)*2+0], w11 = W_fr[(f+1)*2+1];
    const float w20 = W_fr[(f+2)*2+0], w21 = W_fr[(f+2)*2+1];
    const float w30 = W_fr[(f+3)*2+0], w31 = W_fr[(f+3)*2+1];
    const float bf0 = b_fr[0], bf1 = b_fr[1];

    for (int it = 0; it < K1_ROWS/8; ++it){
        const int r0 = rbase + it*8 + wave*2;
        const size_t base = (size_t)r0 * N_IN + 4*lane;
        const float4 xv = *reinterpret_cast<const float4*>(x + base);
        *reinterpret_cast<float4*>(out + base) = xv;       // fused copy
        double p0 = (double)xv.x*w00 + (double)xv.y*w10 + (double)xv.z*w20 + (double)xv.w*w30;
        double p1 = (double)xv.x*w01 + (double)xv.y*w11 + (double)xv.z*w21 + (double)xv.w*w31;
        #pragma unroll
        for (int off = 16; off; off >>= 1){
            p0 += __shfl_xor(p0, off, 32);
            p1 += __shfl_xor(p1, off, 32);
        }
        const unsigned k0 = keyOf((float)(p0 + bf0));
        const unsigned k1 = keyOf((float)(p1 + bf1));
        const int r = r0 + (lane >> 5);
        if ((lane & 31) == 0){ keys[r]     = k0; atomicAdd(&h0[k0 >> 21], 1u); }
        if ((lane & 31) == 1){ keys[N + r] = k1; atomicAdd(&h1[k1 >> 21], 1u); }
    }
    __syncthreads();
    const int slot = c & (HSLOTS-1);
    unsigned* gh0 = gHist + ((size_t)(2*b)   * HSLOTS + slot) * 2048;
    unsigned* gh1 = gHist + ((size_t)(2*b+1) * HSLOTS + slot) * 2048;
    for (int bin = tid; bin < 2048; bin += 256){
        const unsigned s0 = h0[bin], s1 = h1[bin];
        if (s0) atomicAdd(&gh0[bin], s0);
        if (s1) atomicAdd(&gh1[bin], s1);
    }
}

// ---------------------------------------------------------------------------
// Kernel 2: single-scan select + gather.
// Per (group,chunk) block: (a) redundant threshold -> B1; (b) one keys scan
// that BOTH collects boundary-bucket candidates AND compacts/gathers the
// sure-selected rows (bucket > B1) into lists + fp64 partial sums; (c) per-
// group last block refines exact utar/T, appends+gathers the boundary-bucket
// selected rows. No mask, no second scan.
// ---------------------------------------------------------------------------
__global__ __launch_bounds__(1024) void select_gather_kernel(
        const unsigned* __restrict__ keys, const unsigned* __restrict__ gHist,
        const float* __restrict__ x,
        unsigned* __restrict__ gCandCnt, int* __restrict__ cand,
        int* __restrict__ lists, unsigned* __restrict__ gListCnt,
        double* __restrict__ part,
        unsigned* __restrict__ gParams, unsigned* __restrict__ gDone,
        int N, int R)
{
    const int g = blockIdx.x >> 4, ch = blockIdx.x & 15;
    const int b = g >> 1, v = g & 1;
    const unsigned* kk = keys + (size_t)v * N + (size_t)b * R;
    const float* xb = x + (size_t)b * R * N_IN;
    const int tid = threadIdx.x, wave = tid >> 6, lane = tid & 63;
    const int s = tid >> 5;              // row slot 0..31
    const int c4 = (tid & 31) * 4;       // column group

    __shared__ unsigned lh[2048];
    __shared__ unsigned coarse[32];
    __shared__ unsigned sB[2];
    __shared__ unsigned wcntC[16], wcntS[16];
    __shared__ unsigned sLocC, sSubBase;
    __shared__ int slist[1024];
    __shared__ unsigned nccs[CHUNKS];
    __shared__ unsigned sOld;
    __shared__ double red[32][128];

    // ---- (a) per-group threshold (redundant per block) ----
    {
        const unsigned* gh = gHist + (size_t)g * HSLOTS * 2048;
        for (int bin = tid; bin < 2048; bin += 1024){
            unsigned ss = 0;
            #pragma unroll
            for (int sl = 0; sl < HSLOTS; ++sl) ss += gh[sl*2048 + bin];
            lh[bin] = ss;
        }
        __syncthreads();
        if (tid < 32){ unsigned ss = 0; for (int j = 0; j < 64; ++j) ss += lh[tid*64+j]; coarse[tid] = ss; }
        __syncthreads();
        if (tid == 0){
            unsigned kneed = KSEL, cum = 0; int cb = 31;
            for (; cb > 0; --cb){ if (cum + coarse[cb] >= kneed) break; cum += coarse[cb]; }
            int bin = cb*64 + 63;
            for (; bin > cb*64; --bin){ if (cum + lh[bin] >= kneed) break; cum += lh[bin]; }
            sB[0] = (unsigned)bin; sB[1] = kneed - cum;
        }
        __syncthreads();
    }
    const unsigned B1 = sB[0], kneed1 = sB[1];

    // ---- (b) fused scan: candidates (==B1) + sure rows (>B1) with gather ----
    int* cd = cand + (size_t)g * CAND_CAP + ch * SUBCAP;
    int* lst = lists + g * KSEL;
    {
        const int span = R / CHUNKS;
        const int lo = ch * span, hi = lo + span;
        if (tid == 0) sLocC = 0u;
        double a0 = 0.0, a1 = 0.0, a2 = 0.0, a3 = 0.0;
        __syncthreads();
        for (int i0 = lo; i0 < hi; i0 += 1024){
            const int i = i0 + tid;
            const bool valid = i < hi;
            const unsigned u = valid ? kk[i] : 0u;
            const unsigned bkt = u >> 21;
            const bool predC = valid && (bkt == B1);
            const bool predS = valid && (bkt > B1);
            unsigned long long mC = __ballot(predC);
            unsigned long long mS = __ballot(predS);
            if (lane == 0){ wcntC[wave] = (unsigned)__popcll(mC); wcntS[wave] = (unsigned)__popcll(mS); }
            __syncthreads();
            unsigned preC = sLocC, totC = 0, preS = 0, totS = 0;
            #pragma unroll
            for (int w = 0; w < 16; ++w){
                unsigned cC = wcntC[w], cS = wcntS[w];
                if (w < wave){ preC += cC; preS += cS; }
                totC += cC; totS += cS;
            }
            if (predC){
                const unsigned p = preC + (unsigned)__popcll(mC & ((1ULL << lane) - 1ULL));
                if (p < (unsigned)SUBCAP) cd[p] = i;
            }
            if (tid == 0) sSubBase = totS ? atomicAdd(&gListCnt[g*16], totS) : 0u;
            const unsigned locS = preS + (unsigned)__popcll(mS & ((1ULL << lane) - 1ULL));
            if (predS) slist[locS] = i;
            __syncthreads();
            if (predS) lst[sSubBase + locS] = i;
            for (int rr = s; rr < (int)totS; rr += 32){
                const float4 xv = *reinterpret_cast<const float4*>(xb + (size_t)slist[rr] * N_IN + c4);
                a0 += xv.x; a1 += xv.y; a2 += xv.z; a3 += xv.w;
            }
            __syncthreads();
            if (tid == 0) sLocC += totC;
            __syncthreads();
        }
        if (tid == 0) gCandCnt[g*CHUNKS + ch] = min(sLocC, (unsigned)SUBCAP);
        // reduce sure-gather partial into this chunk's slot
        red[s][c4+0] = a0; red[s][c4+1] = a1; red[s][c4+2] = a2; red[s][c4+3] = a3;
        __syncthreads();
        #pragma unroll
        for (int stride = 16; stride >= 1; stride >>= 1){
            if (s < stride){
                red[s][c4+0] += red[s+stride][c4+0];
                red[s][c4+1] += red[s+stride][c4+1];
                red[s][c4+2] += red[s+stride][c4+2];
                red[s][c4+3] += red[s+stride][c4+3];
            }
            __syncthreads();
        }
        if (s == 0){
            double* pp = part + ((size_t)g * PSLOT + ch) * N_IN;
            pp[c4+0] = red[0][c4+0]; pp[c4+1] = red[0][c4+1];
            pp[c4+2] = red[0][c4+2]; pp[c4+3] = red[0][c4+3];
        }
    }

    // ---- (c) last chunk of this group refines + boundary gather ----
    __threadfence();
    if (tid == 0) sOld = atomicAdd(&gDone[g], 1u);
    __syncthreads();
    if (sOld != CHUNKS-1) return;
    __threadfence();   // acquire

    if (tid < CHUNKS) nccs[tid] = gCandCnt[g*CHUNKS + tid];
    const int* cd0 = cand + (size_t)g * CAND_CAP;

    // phase B: bits 20..10 (descending)
    for (int i = tid; i < 2048; i += 1024) lh[i] = 0u;
    __syncthreads();
    for (int ch2 = 0; ch2 < CHUNKS; ++ch2){
        const int n = (int)nccs[ch2]; const int* cdp = cd0 + ch2*SUBCAP;
        for (int i = tid; i < n; i += 1024)
            atomicAdd(&lh[(kk[cdp[i]] >> 10) & 0x7FFu], 1u);
    }
    __syncthreads();
    if (tid < 32){ unsigned ss = 0; for (int j = 0; j < 64; ++j) ss += lh[tid*64+j]; coarse[tid] = ss; }
    __syncthreads();
    if (tid == 0){
        unsigned kneed = kneed1, cum = 0; int cb = 31;
        for (; cb > 0; --cb){ if (cum + coarse[cb] >= kneed) break; cum += coarse[cb]; }
        int bin = cb*64 + 63;
        for (; bin > cb*64; --bin){ if (cum + lh[bin] >= kneed) break; cum += lh[bin]; }
        sB[0] = (unsigned)bin; sB[1] = kneed - cum;
    }
    __syncthreads();
    const unsigned B2 = sB[0], kneed2 = sB[1];
    const unsigned top22 = (B1 << 11) | B2;
    __syncthreads();

    // phase C: low 10 bits (descending)
    for (int i = tid; i < 1024; i += 1024) lh[i] = 0u;
    __syncthreads();
    for (int ch2 = 0; ch2 < CHUNKS; ++ch2){
        const int n = (int)nccs[ch2]; const int* cdp = cd0 + ch2*SUBCAP;
        for (int i = tid; i < n; i += 1024){
            const unsigned u = kk[cdp[i]];
            if ((u >> 10) == top22) atomicAdd(&lh[u & 0x3FFu], 1u);
        }
    }
    __syncthreads();
    if (tid < 32){ unsigned ss = 0; for (int j = 0; j < 32; ++j) ss += lh[tid*32+j]; coarse[tid] = ss; }
    __syncthreads();
    if (tid == 0){
        unsigned kneed = kneed2, cum = 0; int cb = 31;
        for (; cb > 0; --cb){ if (cum + coarse[cb] >= kneed) break; cum += coarse[cb]; }
        int bin = cb*32 + 31;
        for (; bin > cb*32; --bin){ if (cum + lh[bin] >= kneed) break; cum += lh[bin]; }
        sB[0] = (unsigned)bin; sB[1] = kneed - cum;
    }
    __syncthreads();
    const unsigned B3 = sB[0], take_eq = sB[1];
    const unsigned utar = (B1 << 21) | (B2 << 10) | B3;
    __syncthreads();

    // phase T1: hist of idx>>7 among ties (ascending)
    for (int i = tid; i < 1024; i += 1024) lh[i] = 0u;
    __syncthreads();
    for (int ch2 = 0; ch2 < CHUNKS; ++ch2){
        const int n = (int)nccs[ch2]; const int* cdp = cd0 + ch2*SUBCAP;
        for (int i = tid; i < n; i += 1024){
            const int ix = cdp[i];
            if (kk[ix] == utar) atomicAdd(&lh[ix >> 7], 1u);
        }
    }
    __syncthreads();
    if (tid < 32){ unsigned ss = 0; for (int j = 0; j < 32; ++j) ss += lh[tid*32+j]; coarse[tid] = ss; }
    __syncthreads();
    if (tid == 0){
        unsigned need = take_eq, cum = 0; int cb = 0;
        for (; cb < 31; ++cb){ if (cum + coarse[cb] >= need) break; cum += coarse[cb]; }
        int bin = cb*32;
        for (; bin < cb*32+31; ++bin){ if (cum + lh[bin] >= need) break; cum += lh[bin]; }
        sB[0] = (unsigned)bin; sB[1] = need - cum;
    }
    __syncthreads();
    const unsigned cb7 = sB[0], rem = sB[1];
    __syncthreads();

    // phase T2: low 7 index bits (ascending)
    for (int i = tid; i < 128; i += 1024) lh[i] = 0u;
    __syncthreads();
    for (int ch2 = 0; ch2 < CHUNKS; ++ch2){
        const int n = (int)nccs[ch2]; const int* cdp = cd0 + ch2*SUBCAP;
        for (int i = tid; i < n; i += 1024){
            const int ix = cdp[i];
            if (kk[ix] == utar && (unsigned)(ix >> 7) == cb7) atomicAdd(&lh[ix & 127], 1u);
        }
    }
    __syncthreads();
    if (tid == 0){
        unsigned need = rem, cum = 0; int p = 0;
        for (; p < 127; ++p){ if (cum + lh[p] >= need) break; cum += lh[p]; }
        gParams[g*8+2] = utar;
        gParams[g*8+3] = cb7*128 + (unsigned)p;   // T
    }
    __syncthreads();
    const unsigned utarF = gParams[g*8+2];
    const int Tf = (int)gParams[g*8+3];

    // ---- boundary-bucket selected: append to list + gather partial ----
    {
        double a0 = 0.0, a1 = 0.0, a2 = 0.0, a3 = 0.0;
        for (int ch2 = 0; ch2 < CHUNKS; ++ch2){
            const int n = (int)nccs[ch2]; const int* cdp = cd0 + ch2*SUBCAP;
            for (int i0 = 0; i0 < n; i0 += 1024){
                const int i = i0 + tid;
                const bool valid = i < n;
                const int ix = valid ? cdp[i] : 0;
                const unsigned u = valid ? kk[ix] : 0u;
                const bool sel = valid && (u > utarF || (u == utarF && ix <= Tf));
                unsigned long long m = __ballot(sel);
                if (lane == 0) wcntS[wave] = (unsigned)__popcll(m);
                __syncthreads();
                unsigned pre = 0, tot = 0;
                #pragma unroll
                for (int w = 0; w < 16; ++w){ unsigned cc = wcntS[w]; if (w < wave) pre += cc; tot += cc; }
                if (tid == 0) sSubBase = tot ? atomicAdd(&gListCnt[g*16], tot) : 0u;
                const unsigned loc = pre + (unsigned)__popcll(m & ((1ULL << lane) - 1ULL));
                if (sel) slist[loc] = ix;
                __syncthreads();
                if (sel) lst[sSubBase + loc] = ix;
                for (int rr = s; rr < (int)tot; rr += 32){
                    const float4 xv = *reinterpret_cast<const float4*>(xb + (size_t)slist[rr] * N_IN + c4);
                    a0 += xv.x; a1 += xv.y; a2 += xv.z; a3 += xv.w;
                }
                __syncthreads();
            }
        }
        red[s][c4+0] = a0; red[s][c4+1] = a1; red[s][c4+2] = a2; red[s][c4+3] = a3;
        __syncthreads();
        #pragma unroll
        for (int stride = 16; stride >= 1; stride >>= 1){
            if (s < stride){
                red[s][c4+0] += red[s+stride][c4+0];
                red[s][c4+1] += red[s+stride][c4+1];
                red[s][c4+2] += red[s+stride][c4+2];
                red[s][c4+3] += red[s+stride][c4+3];
            }
            __syncthreads();
        }
        if (s == 0){
            double* pp = part + ((size_t)g * PSLOT + 16) * N_IN;
            pp[c4+0] = red[0][c4+0]; pp[c4+1] = red[0][c4+1];
            pp[c4+2] = red[0][c4+2]; pp[c4+3] = red[0][c4+3];
        }
    }
}

// ---------------------------------------------------------------------------
// Kernel 3: redundant tiny MLP (fp64, proven) + sparse blend over the exact-K
// selection lists; dedup across v via key-predicate probes (no mask).
// ---------------------------------------------------------------------------
__global__ __launch_bounds__(256) void update_mlp_kernel(
        const float* __restrict__ x, const unsigned* __restrict__ keys,
        const int* __restrict__ lists, const double* __restrict__ part,
        const unsigned* __restrict__ gParams,
        const float* __restrict__ W1, const float* __restrict__ b1,
        const float* __restrict__ W2, const float* __restrict__ b2,
        float* __restrict__ out, int N, int R)
{
    const int g = blockIdx.x >> 4, sl = blockIdx.x & (USLICE-1);
    const int b = g >> 1, v = g & 1;
    const int tid = threadIdx.x;

    __shared__ __align__(16) float inv[DD];
    __shared__ __align__(16) float h1s[DD];
    __shared__ __align__(16) float u[DD];

    {
        const int g2 = b*2 + (tid >> 7);
        const int fcol = tid & 127;
        double ssum = 0.0;
        for (int cc = 0; cc < PSLOT; ++cc) ssum += part[((size_t)g2 * PSLOT + cc) * N_IN + fcol];
        inv[tid] = (float)(ssum / (double)KSEL);
    }
    __syncthreads();
    {
        double a0=0, a1=0, a2=0, a3=0;
        for (int i = 0; i < DD; i += 4){
            a0 += (double)inv[i+0] * (double)W1[(i+0)*DD + tid];
            a1 += (double)inv[i+1] * (double)W1[(i+1)*DD + tid];
            a2 += (double)inv[i+2] * (double)W1[(i+2)*DD + tid];
            a3 += (double)inv[i+3] * (double)W1[(i+3)*DD + tid];
        }
        h1s[tid] = fmaxf((float)(((a0+a1)+(a2+a3)) + (double)b1[tid]), 0.0f);
    }
    __syncthreads();
    {
        double a0=0, a1=0, a2=0, a3=0;
        for (int i = 0; i < DD; i += 4){
            a0 += (double)h1s[i+0] * (double)W2[(i+0)*DD + tid];
            a1 += (double)h1s[i+1] * (double)W2[(i+1)*DD + tid];
            a2 += (double)h1s[i+2] * (double)W2[(i+2)*DD + tid];
            a3 += (double)h1s[i+3] * (double)W2[(i+3)*DD + tid];
        }
        u[tid] = (float)(((a0+a1)+(a2+a3)) + (double)b2[tid]);
    }
    __syncthreads();

    const int wave = tid >> 6, lane = tid & 63;
    const int half = lane >> 5;
    const int c4 = (lane & 31) * 4;
    const int* lst = lists + g * KSEL + sl * (KSEL/USLICE);
    const unsigned* k0p = keys + (size_t)b * R;                 // v=0 keys
    const unsigned* k1p = keys + (size_t)N + (size_t)b * R;     // v=1 keys
    const unsigned utar0 = gParams[(b*2+0)*8+2];
    const int      T0    = (int)gParams[(b*2+0)*8+3];
    const unsigned utar1 = gParams[(b*2+1)*8+2];
    const int      T1    = (int)gParams[(b*2+1)*8+3];
    const float4 u0 = *reinterpret_cast<const float4*>(&u[c4]);
    const float4 u1 = *reinterpret_cast<const float4*>(&u[128 + c4]);
    const size_t rowBase = (size_t)b * R;

    for (int e = wave*2 + half; e < KSEL/USLICE; e += 8){
        const int row = lst[e];
        if (v == 1){
            const unsigned uk0 = k0p[row];
            if (uk0 > utar0 || (uk0 == utar0 && row <= T0)) continue;  // v0 pass handles
        }
        const size_t base = (rowBase + row) * N_IN + c4;
        float4 o = *reinterpret_cast<const float4*>(x + base);
        if (v == 0){
            o.x = (o.x + u0.x)*0.5f; o.y = (o.y + u0.y)*0.5f;
            o.z = (o.z + u0.z)*0.5f; o.w = (o.w + u0.w)*0.5f;
            const unsigned uk1 = k1p[row];
            if (uk1 > utar1 || (uk1 == utar1 && row <= T1)){
                o.x = (o.x + u1.x)*0.5f; o.y = (o.y + u1.y)*0.5f;
                o.z = (o.z + u1.z)*0.5f; o.w = (o.w + u1.w)*0.5f;
            }
        } else {
            o.x = (o.x + u1.x)*0.5f; o.y = (o.y + u1.y)*0.5f;
            o.z = (o.z + u1.z)*0.5f; o.w = (o.w + u1.w)*0.5f;
        }
        *reinterpret_cast<float4*>(out + base) = o;
    }
}

extern "C" void kernel_launch(void* const* d_in, const int* in_sizes, int n_in_cnt,
                              void* d_out, int out_size, void* d_ws, size_t ws_size,
                              hipStream_t stream)
{
    const float* x    = (const float*)d_in[0];
    const float* W_fr = (const float*)d_in[1];
    const float* b_fr = (const float*)d_in[2];
    const float* W1   = (const float*)d_in[3];
    const float* b1   = (const float*)d_in[4];
    const float* W2   = (const float*)d_in[5];
    const float* b2   = (const float*)d_in[6];
    float* out = (float*)d_out;

    const int N = in_sizes[0] / N_IN;   // 800000
    const int R = N / NBATCH;           // 100000

    char* ws = (char*)d_ws;
    size_t off = 0;
    auto alloc = [&](size_t bytes) -> void* {
        void* p = ws + off;
        off = (off + bytes + 255) & ~(size_t)255;
        return p;
    };
    int*      lists   = (int*)     alloc((size_t)NGROUP * KSEL * 4);
    double*   part    = (double*)  alloc((size_t)NGROUP * PSLOT * N_IN * 8);
    unsigned* gParams = (unsigned*)alloc((size_t)NGROUP * 8 * 4);
    unsigned* gCandCnt= (unsigned*)alloc((size_t)NGROUP * CHUNKS * 4);

    const size_t zrBytes = 256 + 4096 + (size_t)NGROUP * HSLOTS * 2048 * 4;
    char*     zr       = (char*)    alloc(zrBytes);
    unsigned* gDone    = (unsigned*)zr;                  // 16 counters
    unsigned* gListCnt = (unsigned*)(zr + 256);          // 16 groups * 64B lines
    unsigned* gHist    = (unsigned*)(zr + 256 + 4096);
    unsigned* keys     = (unsigned*)alloc((size_t)2 * N * 4);
    int*      cand     = (int*)     alloc((size_t)NGROUP * CAND_CAP * 4);

    const int n16 = (int)(zrBytes / 16);
    zero_kernel<<<dim3((n16 + 255) / 256), dim3(256), 0, stream>>>((uint4*)zr, n16);
    scores_hist_copy_kernel<<<dim3(NBATCH*K1_CPB), dim3(256), 0, stream>>>(
        x, W_fr, b_fr, keys, gHist, out, N, R);
    select_gather_kernel<<<dim3(NGROUP*CHUNKS), dim3(1024), 0, stream>>>(
        keys, gHist, x, gCandCnt, cand, lists, gListCnt, part, gParams, gDone, N, R);
    update_mlp_kernel<<<dim3(NGROUP*USLICE), dim3(256), 0, stream>>>(
        x, keys, lists, part, gParams, W1, b1, W2, b2, out, N, R);
}